// Round 16
// baseline (569.986 us; speedup 1.0000x reference)
//
#include <hip/hip_runtime.h>
#include <cstdint>
#include <cstddef>

// Problem constants
#define BATCH   16
#define SEQ     512
#define NTOK    8192        // BATCH*SEQ
#define DMODEL  512
#define NHEAD   8
#define HDIM    64
#define FFDIM   2048
#define NLAYER  4

typedef unsigned short u16;
typedef __attribute__((ext_vector_type(8))) short bf16x8;
typedef __attribute__((ext_vector_type(8))) unsigned short us8;
typedef __attribute__((ext_vector_type(4))) float f32x4;

__device__ __forceinline__ float bf2f(u16 u) {
    union { float f; unsigned int i; } x; x.i = ((unsigned int)u) << 16; return x.f;
}
__device__ __forceinline__ u16 f2b(float f) {
    union { float f; unsigned int u; } a; a.f = f;
    unsigned int r = a.u + 0x7fff + ((a.u >> 16) & 1);   // round-nearest-even
    return (u16)(r >> 16);
}

// async global->LDS 16B copy (global_load_lds_dwordx4)
__device__ __forceinline__ void async_copy16(const void* g, void* l) {
    __builtin_amdgcn_global_load_lds(
        (const __attribute__((address_space(1))) unsigned int*)g,
        (__attribute__((address_space(3))) unsigned int*)l, 16, 0, 0);
}

// ---------------------------------------------------------------------------
// Embed: writes bf16 xb only
// ---------------------------------------------------------------------------
__global__ __launch_bounds__(256) void embed_kernel(
    const float* __restrict__ feat, const int* __restrict__ pos,
    const float* __restrict__ w_in, const float* __restrict__ b_in,
    u16* __restrict__ xb)
{
    int idx = blockIdx.x * 256 + threadIdx.x;
    if (idx >= NTOK * DMODEL) return;
    int t = idx >> 9;
    int d = idx & 511;
    float acc = b_in[d];
#pragma unroll
    for (int i = 0; i < 8; ++i)
        acc += feat[t * 8 + i] * w_in[i * DMODEL + d];
    int p = pos[t];
    int dl = d & 63;
    int pair = dl >> 1;
    float div = expf(-(float)(2 * pair) * 0.14391156831212787f);
    float ang = (float)p * div;
    float pe = (dl & 1) ? cosf(ang) : sinf(ang);
    xb[idx] = f2b(acc + pe);
}

// ---------------------------------------------------------------------------
// Weight transpose + bf16 convert: W [K,N] -> WT [N,K], batched over L
// ---------------------------------------------------------------------------
__global__ __launch_bounds__(256) void transpose_w_kernel(
    const float* __restrict__ W, u16* __restrict__ WT, int K, int N)
{
    __shared__ float t[32][33];
    const float* Wl = W + (size_t)blockIdx.z * K * N;
    u16* WTl = WT + (size_t)blockIdx.z * K * N;
    int n0 = blockIdx.x * 32, k0 = blockIdx.y * 32;
    int c = threadIdx.x & 31, r8 = threadIdx.x >> 5;
#pragma unroll
    for (int i = 0; i < 4; ++i) {
        int r = r8 + i * 8;
        t[r][c] = Wl[(size_t)(k0 + r) * N + n0 + c];
    }
    __syncthreads();
#pragma unroll
    for (int i = 0; i < 4; ++i) {
        int r = r8 + i * 8;
        WTl[(size_t)(n0 + r) * K + k0 + c] = f2b(t[c][r]);
    }
}

// ---------------------------------------------------------------------------
// 128xNT bf16 MFMA GEMM — R15-proven drain-after-MFMA schedule, templated on
// N-tile (NT=128 proven; NT=256 doubles MFMA-per-drain: 64 vs 32 at 1.5x the
// staging — targets the measured stall:compute imbalance, MfmaUtil 15%).
// Order per tile: read ALL frags; barrier; stage(t+1) overwrites; MFMA(regs);
// barrier(drain). Single buffer, pure __syncthreads semantics.
// NT=256: 4 waves 2Mx2N, per-wave 64x128 (4x8 frags); ~245 VGPR (no spill
// expected, m08: clean through 450); LDS 48KB.
// Keeps: BK=64, XOR chunk-swizzle (0 conflicts), XCD block swizzle, setprio,
// bf16-thinned epilogue with fused bias/resid/relu.
// ---------------------------------------------------------------------------
template <int NT, int RELU, int ADD_RESID>
__global__ __launch_bounds__(256) void gemm_bk64_kernel(
    const u16* __restrict__ A, const u16* __restrict__ BT,
    const float* __restrict__ bias, const u16* __restrict__ resid,
    u16* __restrict__ C, int M, int N, int K)
{
    constexpr int NJ = NT / 32;           // per-wave N frags (4 or 8)
    __shared__ u16 As[128 * 64];
    __shared__ u16 Bs[NT * 64];
    const int tid = threadIdx.x;

    // XCD-locality swizzle (bijection; gy%8==0 at all call sites)
    const int gx = gridDim.x, gy = gridDim.y;
    const int raw = blockIdx.x + gx * blockIdx.y;
    const int xcd = raw & 7;
    const int k8  = raw >> 3;
    const int ych = gy >> 3;
    const int m0 = (xcd * ych + k8 / gx) * 128;
    const int n0 = (k8 % gx) * NT;

    const int wid = tid >> 6, lane = tid & 63;
    const int wr = (wid >> 1) * 64, wc = (wid & 1) * (NT / 2);
    const int lr = lane & 15, lk16 = lane >> 4;
    const int sw = lr & 7;

    f32x4 acc[4][NJ] = {};
    const int T = K >> 6;

#define STAGE_TILE(kt)                                                         \
    {                                                                          \
        _Pragma("unroll")                                                      \
        for (int u = 0; u < 4; ++u) {                                          \
            int cc = u * 256 + tid;                                            \
            int row = cc >> 3, kc = cc & 7;                                    \
            async_copy16(&A[(size_t)(m0 + row) * K + (kt) + ((kc ^ (row & 7)) * 8)], \
                         &As[cc * 8]);                                         \
        }                                                                      \
        _Pragma("unroll")                                                      \
        for (int u = 0; u < NT / 32; ++u) {                                    \
            int cc = u * 256 + tid;                                            \
            int row = cc >> 3, kc = cc & 7;                                    \
            async_copy16(&BT[(size_t)(n0 + row) * K + (kt) + ((kc ^ (row & 7)) * 8)], \
                         &Bs[cc * 8]);                                         \
        }                                                                      \
    }

    STAGE_TILE(0);
    __syncthreads();                      // tile 0 in LDS

    for (int t = 0; t < T; ++t) {
        // read fragments of tile t
        bf16x8 a[4][2], b[NJ][2];
#pragma unroll
        for (int i = 0; i < 4; ++i)
#pragma unroll
            for (int kk = 0; kk < 2; ++kk)
                a[i][kk] = *(const bf16x8*)&As[
                    (wr + i * 16 + lr) * 64 + (((kk * 4 + lk16) ^ sw) * 8)];
#pragma unroll
        for (int j = 0; j < NJ; ++j)
#pragma unroll
            for (int kk = 0; kk < 2; ++kk)
                b[j][kk] = *(const bf16x8*)&Bs[
                    (wc + j * 16 + lr) * 64 + (((kk * 4 + lk16) ^ sw) * 8)];

        __syncthreads();                  // ALL waves' reads of tile t done
        if (t + 1 < T) STAGE_TILE((t + 1) * 64);  // safe overwrite; in flight

        __builtin_amdgcn_s_setprio(1);
#pragma unroll
        for (int i = 0; i < 4; ++i)
#pragma unroll
            for (int j = 0; j < NJ; ++j)
#pragma unroll
                for (int kk = 0; kk < 2; ++kk)
                    acc[i][j] = __builtin_amdgcn_mfma_f32_16x16x32_bf16(
                        a[i][kk], b[j][kk], acc[i][j], 0, 0, 0);
        __builtin_amdgcn_s_setprio(0);

        __syncthreads();                  // drain (vmcnt 0): tile t+1 landed
    }
#undef STAGE_TILE

    // Epilogue: D[row=(lane>>4)*4+r][col=lane&15] per fragment (m89 map)
#pragma unroll
    for (int j = 0; j < NJ; ++j) {
        int col = n0 + wc + j * 16 + lr;
        float bb = bias[col];
#pragma unroll
        for (int i = 0; i < 4; ++i) {
            int rbase = m0 + wr + i * 16 + lk16 * 4;
            f32x4 v = acc[i][j];
#pragma unroll
            for (int r = 0; r < 4; ++r) {
                float val = v[r] + bb;
                if (ADD_RESID) val += bf2f(resid[(size_t)(rbase + r) * N + col]);
                if (RELU) val = fmaxf(val, 0.f);
                C[(size_t)(rbase + r) * N + col] = f2b(val);
            }
        }
    }
}

// ---------------------------------------------------------------------------
// MFMA flash attention — R16: QBLK=128 (2 q-tiles per block share one K/V
// staging pass; staging cost per unit work halves; grid 1024->512).
// Ps per-wave buffer reused sequentially across q-sets (same-wave DS ops are
// in-order -> WAR safe). Fixed-reference softmax (R10), ones-MFMA l (R15),
// pipelined K/V staging (R9), XCD decode (R8).
// ---------------------------------------------------------------------------
__global__ __launch_bounds__(256) void attention_mfma_kernel(
    const u16* __restrict__ qkv, u16* __restrict__ ctx)
{
    __shared__ __align__(16) u16 Ks[2][64 * 64];
    __shared__ __align__(16) u16 Vt[64][72];
    __shared__ __align__(16) u16 Ps[4][16][72];

    const int tid = threadIdx.x;
    // 512 blocks: xcd owns 16 (b,h) pairs x 4 q-tiles of 128
    const int raw = blockIdx.x;
    const int xcd = raw & 7;
    const int k8  = raw >> 3;            // 0..63
    const int bh  = xcd * 16 + (k8 >> 2);  // 0..127
    const int b = bh >> 3, h = bh & 7;
    const int q0 = (k8 & 3) * 128;

    const int wid = tid >> 6, lane = tid & 63;
    const int lr = lane & 15;
    const int lk16 = lane >> 4;
    const size_t base = (size_t)b * SEQ * 1536;
    const int qrow = wid * 16 + lr;

    // Q fragments in registers, both q-sets
    bf16x8 qf[2][2];
#pragma unroll
    for (int qs = 0; qs < 2; ++qs)
#pragma unroll
        for (int ks = 0; ks < 2; ++ks)
            qf[qs][ks] = *(const bf16x8*)&qkv[base + (size_t)(q0 + qs * 64 + qrow) * 1536
                                              + h * 64 + ks * 32 + lk16 * 8];

    // all-ones bf16 B-fragment (1.0 = 0x3F80)
    bf16x8 ones;
#pragma unroll
    for (int e = 0; e < 8; ++e) ones[e] = (short)0x3F80;

    const int vr0 = tid & 63;
    const int vc0 = (tid >> 6) * 8;
    const int vc1 = 32 + vc0;

    // ---- Prologue: stage tile 0
#pragma unroll
    for (int j = 0; j < 2; ++j) {
        int c = j * 256 + tid;
        int row = c >> 3;
        int sc8 = ((c & 7) ^ (row & 7)) * 8;
        async_copy16(&qkv[base + (size_t)(row) * 1536 + 512 + h * 64 + sc8], &Ks[0][c * 8]);
    }
    us8 v0 = *(const us8*)&qkv[base + (size_t)(vr0) * 1536 + 1024 + h * 64 + vc0];
    us8 v1 = *(const us8*)&qkv[base + (size_t)(vr0) * 1536 + 1024 + h * 64 + vc1];
    __syncthreads();
#pragma unroll
    for (int e = 0; e < 8; ++e) { Vt[vc0 + e][vr0] = v0[e]; Vt[vc1 + e][vr0] = v1[e]; }
    __syncthreads();

    f32x4 l_acc[2] = {};
    f32x4 o_acc[2][4] = {};
    const float SC2 = 0.18033688011112042f;   // 0.125 * log2(e)

    for (int t = 0; t < SEQ / 64; ++t) {
        const int cur = t & 1;
        const bool more = (t + 1 < SEQ / 64);
        if (more) {
            const int kt1 = (t + 1) * 64;
#pragma unroll
            for (int j = 0; j < 2; ++j) {
                int c = j * 256 + tid;
                int row = c >> 3;
                int sc8 = ((c & 7) ^ (row & 7)) * 8;
                async_copy16(&qkv[base + (size_t)(kt1 + row) * 1536 + 512 + h * 64 + sc8],
                             &Ks[cur ^ 1][c * 8]);
            }
            v0 = *(const us8*)&qkv[base + (size_t)(kt1 + vr0) * 1536 + 1024 + h * 64 + vc0];
            v1 = *(const us8*)&qkv[base + (size_t)(kt1 + vr0) * 1536 + 1024 + h * 64 + vc1];
        }

#pragma unroll
        for (int qs = 0; qs < 2; ++qs) {
            // QK^T (q-set qs) on tile t
            f32x4 sc[4] = {};
#pragma unroll
            for (int ks = 0; ks < 2; ++ks) {
#pragma unroll
                for (int j = 0; j < 4; ++j) {
                    int krow = j * 16 + lr;
                    bf16x8 bk = *(const bf16x8*)&Ks[cur][krow * 64 + ((ks * 4 + lk16) ^ (krow & 7)) * 8];
                    sc[j] = __builtin_amdgcn_mfma_f32_16x16x32_bf16(qf[qs][ks], bk, sc[j], 0, 0, 0);
                }
            }

            // fixed-reference softmax -> Ps (bf16); same-wave reuse across qs
#pragma unroll
            for (int j = 0; j < 4; ++j)
#pragma unroll
                for (int r = 0; r < 4; ++r)
                    Ps[wid][lk16 * 4 + r][j * 16 + lr] =
                        f2b(__builtin_amdgcn_exp2f(sc[j][r] * SC2));

            // PV + l via ones-MFMA
#pragma unroll
            for (int kk = 0; kk < 2; ++kk) {
                bf16x8 ap = *(const bf16x8*)&Ps[wid][lr][kk * 32 + lk16 * 8];
                l_acc[qs] = __builtin_amdgcn_mfma_f32_16x16x32_bf16(ap, ones, l_acc[qs], 0, 0, 0);
#pragma unroll
                for (int j2 = 0; j2 < 4; ++j2) {
                    bf16x8 bv = *(const bf16x8*)&Vt[j2 * 16 + lr][kk * 32 + lk16 * 8];
                    o_acc[qs][j2] = __builtin_amdgcn_mfma_f32_16x16x32_bf16(ap, bv, o_acc[qs][j2], 0, 0, 0);
                }
            }
        }

        __syncthreads();
        if (more) {
#pragma unroll
            for (int e = 0; e < 8; ++e) { Vt[vc0 + e][vr0] = v0[e]; Vt[vc1 + e][vr0] = v1[e]; }
        }
        __syncthreads();
    }

    // epilogue: out[q][d] = o/l, bf16
#pragma unroll
    for (int qs = 0; qs < 2; ++qs)
#pragma unroll
        for (int r = 0; r < 4; ++r) {
            float inv = 1.f / l_acc[qs][r];
            int t = b * SEQ + q0 + qs * 64 + wid * 16 + lk16 * 4 + r;
            u16* op = &ctx[(size_t)t * DMODEL + h * 64];
#pragma unroll
            for (int j2 = 0; j2 < 4; ++j2)
                op[j2 * 16 + lr] = f2b(o_acc[qs][j2][r] * inv);
        }
}

// ---------------------------------------------------------------------------
// LayerNorm over pre-summed bf16 input (residual fused into GEMM epilogue).
// ---------------------------------------------------------------------------
__global__ __launch_bounds__(256) void ln_kernel(
    const u16* __restrict__ sum_in, u16* __restrict__ xb,
    const float* __restrict__ gamma, const float* __restrict__ beta)
{
    const int wave = threadIdx.x >> 6, lane = threadIdx.x & 63;
    const int t = blockIdx.x * 4 + wave;
    const u16* sr = sum_in + (size_t)t * DMODEL;
    u16* xbr = xb + (size_t)t * DMODEL;

    us8 a = *(const us8*)&sr[lane * 8];
    float v[8];
    float sum = 0.f;
#pragma unroll
    for (int i = 0; i < 8; ++i) { v[i] = bf2f(a[i]); sum += v[i]; }
#pragma unroll
    for (int off = 32; off; off >>= 1) sum += __shfl_xor(sum, off);
    float mean = sum * (1.f / DMODEL);
    float vs = 0.f;
#pragma unroll
    for (int i = 0; i < 8; ++i) {
        float d = v[i] - mean;
        vs += d * d;
    }
#pragma unroll
    for (int off = 32; off; off >>= 1) vs += __shfl_xor(vs, off);
    float rstd = rsqrtf(vs * (1.f / DMODEL) + 1e-5f);
    us8 o;
#pragma unroll
    for (int i = 0; i < 8; ++i) {
        int d = lane * 8 + i;
        o[i] = f2b((v[i] - mean) * rstd * gamma[d] + beta[d]);
    }
    *(us8*)&xbr[lane * 8] = o;
}

// ---------------------------------------------------------------------------
// Output projection: reads bf16 xb
// ---------------------------------------------------------------------------
__global__ __launch_bounds__(256) void out_kernel(
    const u16* __restrict__ xb, const float* __restrict__ w,
    const float* __restrict__ b, float* __restrict__ out)
{
    const int wave = threadIdx.x >> 6, lane = threadIdx.x & 63;
    const int t = blockIdx.x * 4 + wave;
    const u16* xr = xb + (size_t)t * DMODEL;
    us8 a = *(const us8*)&xr[lane * 8];
    float acc = 0.f;
#pragma unroll
    for (int i = 0; i < 8; ++i)
        acc += bf2f(a[i]) * w[lane * 8 + i];
#pragma unroll
    for (int off = 32; off; off >>= 1) acc += __shfl_xor(acc, off);
    if (lane == 0) out[t] = acc + b[0];
}

// ---------------------------------------------------------------------------
extern "C" void kernel_launch(void* const* d_in, const int* in_sizes, int n_in,
                              void* d_out, int out_size, void* d_ws, size_t ws_size,
                              hipStream_t stream)
{
    const float* features = (const float*)d_in[0];
    const int*   pos      = (const int*)  d_in[1];
    const float* w_in     = (const float*)d_in[2];
    const float* b_in     = (const float*)d_in[3];
    const float* qkv_w    = (const float*)d_in[4];
    const float* qkv_b    = (const float*)d_in[5];
    const float* ow       = (const float*)d_in[6];
    const float* ob       = (const float*)d_in[7];
    const float* g1       = (const float*)d_in[8];
    const float* b1       = (const float*)d_in[9];
    const float* ff1w     = (const float*)d_in[10];
    const float* ff1b     = (const float*)d_in[11];
    const float* ff2w     = (const float*)d_in[12];
    const float* ff2b     = (const float*)d_in[13];
    const float* g2       = (const float*)d_in[14];
    const float* b2       = (const float*)d_in[15];
    const float* w_out    = (const float*)d_in[16];
    const float* b_out    = (const float*)d_in[17];
    float* out = (float*)d_out;

    char* p = (char*)d_ws;
    auto alloc = [&](size_t bytes) { char* r = p; p += (bytes + 255) & ~(size_t)255; return r; };
    u16*   xb  = (u16*)  alloc((size_t)NTOK * DMODEL * 2);          // 8 MB
    u16*   big = (u16*)  alloc((size_t)NTOK * FFDIM * 2);           // 32 MB
    u16*   ctx = (u16*)  alloc((size_t)NTOK * DMODEL * 2);          // 8 MB
    u16*   tmp = (u16*)  alloc((size_t)NTOK * DMODEL * 2);          // 8 MB
    u16* wqkvT = (u16*)alloc((size_t)NLAYER * DMODEL * 3 * DMODEL * 2);
    u16* owT   = (u16*)alloc((size_t)NLAYER * DMODEL * DMODEL * 2);
    u16* f1wT  = (u16*)alloc((size_t)NLAYER * DMODEL * FFDIM * 2);
    u16* f2wT  = (u16*)alloc((size_t)NLAYER * FFDIM * DMODEL * 2);

    transpose_w_kernel<<<dim3(3 * DMODEL / 32, DMODEL / 32, NLAYER), 256, 0, stream>>>(
        qkv_w, wqkvT, DMODEL, 3 * DMODEL);
    transpose_w_kernel<<<dim3(DMODEL / 32, DMODEL / 32, NLAYER), 256, 0, stream>>>(
        ow, owT, DMODEL, DMODEL);
    transpose_w_kernel<<<dim3(FFDIM / 32, DMODEL / 32, NLAYER), 256, 0, stream>>>(
        ff1w, f1wT, DMODEL, FFDIM);
    transpose_w_kernel<<<dim3(DMODEL / 32, FFDIM / 32, NLAYER), 256, 0, stream>>>(
        ff2w, f2wT, FFDIM, DMODEL);

    embed_kernel<<<(NTOK * DMODEL + 255) / 256, 256, 0, stream>>>(
        features, pos, w_in, b_in, xb);

    for (int l = 0; l < NLAYER; ++l) {
        // qkv = xb @ qkv_w + qkv_b -> bf16 [8192,1536]  (NT=256)
        gemm_bk64_kernel<256, 0, 0><<<dim3(3 * DMODEL / 256, NTOK / 128), 256, 0, stream>>>(
            xb, wqkvT + (size_t)l * DMODEL * 3 * DMODEL, qkv_b + (size_t)l * 3 * DMODEL,
            nullptr, big, NTOK, 3 * DMODEL, DMODEL);
        // attention -> ctx bf16  (512 blocks, QBLK=128)
        attention_mfma_kernel<<<BATCH * NHEAD * (SEQ / 128), 256, 0, stream>>>(big, ctx);
        // tmp = ctx @ ow + ob + xb   (residual fused, NT=128)
        gemm_bk64_kernel<128, 0, 1><<<dim3(DMODEL / 128, NTOK / 128), 256, 0, stream>>>(
            ctx, owT + (size_t)l * DMODEL * DMODEL, ob + (size_t)l * DMODEL, xb,
            tmp, NTOK, DMODEL, DMODEL);
        // xb = LN(tmp)
        ln_kernel<<<NTOK / 4, 256, 0, stream>>>(
            tmp, xb, g1 + (size_t)l * DMODEL, b1 + (size_t)l * DMODEL);
        // h = relu(xb @ ff1w + ff1b) -> bf16 [8192,2048]  (NT=256)
        gemm_bk64_kernel<256, 1, 0><<<dim3(FFDIM / 256, NTOK / 128), 256, 0, stream>>>(
            xb, f1wT + (size_t)l * DMODEL * FFDIM, ff1b + (size_t)l * FFDIM,
            nullptr, big, NTOK, FFDIM, DMODEL);
        // tmp = h @ ff2w + ff2b + xb  (residual fused, NT=128)
        gemm_bk64_kernel<128, 0, 1><<<dim3(DMODEL / 128, NTOK / 128), 256, 0, stream>>>(
            big, f2wT + (size_t)l * FFDIM * DMODEL, ff2b + (size_t)l * DMODEL, xb,
            tmp, NTOK, DMODEL, FFDIM);
        // xb = LN(tmp)
        ln_kernel<<<NTOK / 4, 256, 0, stream>>>(
            tmp, xb, g2 + (size_t)l * DMODEL, b2 + (size_t)l * DMODEL);
    }

    out_kernel<<<NTOK / 4, 256, 0, stream>>>(xb, w_out, b_out, out);
}

// Round 17
// 539.948 us; speedup vs baseline: 1.0556x; 1.0556x over previous
//
#include <hip/hip_runtime.h>
#include <cstdint>
#include <cstddef>

// Problem constants
#define BATCH   16
#define SEQ     512
#define NTOK    8192        // BATCH*SEQ
#define DMODEL  512
#define NHEAD   8
#define HDIM    64
#define FFDIM   2048
#define NLAYER  4

typedef unsigned short u16;
typedef __attribute__((ext_vector_type(8))) short bf16x8;
typedef __attribute__((ext_vector_type(8))) unsigned short us8;
typedef __attribute__((ext_vector_type(4))) float f32x4;

__device__ __forceinline__ float bf2f(u16 u) {
    union { float f; unsigned int i; } x; x.i = ((unsigned int)u) << 16; return x.f;
}
__device__ __forceinline__ u16 f2b(float f) {
    union { float f; unsigned int u; } a; a.f = f;
    unsigned int r = a.u + 0x7fff + ((a.u >> 16) & 1);   // round-nearest-even
    return (u16)(r >> 16);
}

// async global->LDS 16B copy (global_load_lds_dwordx4)
__device__ __forceinline__ void async_copy16(const void* g, void* l) {
    __builtin_amdgcn_global_load_lds(
        (const __attribute__((address_space(1))) unsigned int*)g,
        (__attribute__((address_space(3))) unsigned int*)l, 16, 0, 0);
}

// ---------------------------------------------------------------------------
// Embed: writes bf16 xb only
// ---------------------------------------------------------------------------
__global__ __launch_bounds__(256) void embed_kernel(
    const float* __restrict__ feat, const int* __restrict__ pos,
    const float* __restrict__ w_in, const float* __restrict__ b_in,
    u16* __restrict__ xb)
{
    int idx = blockIdx.x * 256 + threadIdx.x;
    if (idx >= NTOK * DMODEL) return;
    int t = idx >> 9;
    int d = idx & 511;
    float acc = b_in[d];
#pragma unroll
    for (int i = 0; i < 8; ++i)
        acc += feat[t * 8 + i] * w_in[i * DMODEL + d];
    int p = pos[t];
    int dl = d & 63;
    int pair = dl >> 1;
    float div = expf(-(float)(2 * pair) * 0.14391156831212787f);
    float ang = (float)p * div;
    float pe = (dl & 1) ? cosf(ang) : sinf(ang);
    xb[idx] = f2b(acc + pe);
}

// ---------------------------------------------------------------------------
// Weight transpose + bf16 convert: W [K,N] -> WT [N,K], batched over L
// ---------------------------------------------------------------------------
__global__ __launch_bounds__(256) void transpose_w_kernel(
    const float* __restrict__ W, u16* __restrict__ WT, int K, int N)
{
    __shared__ float t[32][33];
    const float* Wl = W + (size_t)blockIdx.z * K * N;
    u16* WTl = WT + (size_t)blockIdx.z * K * N;
    int n0 = blockIdx.x * 32, k0 = blockIdx.y * 32;
    int c = threadIdx.x & 31, r8 = threadIdx.x >> 5;
#pragma unroll
    for (int i = 0; i < 4; ++i) {
        int r = r8 + i * 8;
        t[r][c] = Wl[(size_t)(k0 + r) * N + n0 + c];
    }
    __syncthreads();
#pragma unroll
    for (int i = 0; i < 4; ++i) {
        int r = r8 + i * 8;
        WTl[(size_t)(n0 + r) * K + k0 + c] = f2b(t[c][r]);
    }
}

// ---------------------------------------------------------------------------
// 128x128 bf16 MFMA GEMM — R15-proven (best measured, 541us total):
// single-buffer DRAIN-AFTER-MFMA schedule. Order per tile:
//   read frags; barrier(all reads done); stage(t+1) overwrites; setprio+MFMA
//   (regs only); barrier(DRAIN ~155+cy after issue -> latency hidden).
// Pure __syncthreads semantics. LDS 32KB (4 blocks/CU). BK=64, XOR chunk-
// swizzle (0 conflicts), XCD block swizzle, bf16-thinned epilogue.
// (R16's NT=256 + QBLK=128 bundle regressed +29us -> reverted.)
// ---------------------------------------------------------------------------
template <int RELU, int ADD_RESID>
__global__ __launch_bounds__(256) void gemm_bk64_kernel(
    const u16* __restrict__ A, const u16* __restrict__ BT,
    const float* __restrict__ bias, const u16* __restrict__ resid,
    u16* __restrict__ C, int M, int N, int K)
{
    __shared__ u16 As[128 * 64];
    __shared__ u16 Bs[128 * 64];
    const int tid = threadIdx.x;

    // XCD-locality swizzle (bijection; gy%8==0 at all call sites)
    const int gx = gridDim.x, gy = gridDim.y;
    const int raw = blockIdx.x + gx * blockIdx.y;
    const int xcd = raw & 7;
    const int k8  = raw >> 3;
    const int ych = gy >> 3;
    const int m0 = (xcd * ych + k8 / gx) * 128;
    const int n0 = (k8 % gx) * 128;

    const int wid = tid >> 6, lane = tid & 63;
    const int wr = (wid >> 1) * 64, wc = (wid & 1) * 64;
    const int lr = lane & 15, lk16 = lane >> 4;
    const int sw = lr & 7;

    f32x4 acc[4][4] = {};
    const int T = K >> 6;

#define STAGE_TILE(kt)                                                         \
    {                                                                          \
        _Pragma("unroll")                                                      \
        for (int u = 0; u < 4; ++u) {                                          \
            int cc = u * 256 + tid;                                            \
            int row = cc >> 3, kc = cc & 7;                                    \
            async_copy16(&A[(size_t)(m0 + row) * K + (kt) + ((kc ^ (row & 7)) * 8)], \
                         &As[cc * 8]);                                         \
        }                                                                      \
        _Pragma("unroll")                                                      \
        for (int u = 0; u < 4; ++u) {                                          \
            int cc = u * 256 + tid;                                            \
            int row = cc >> 3, kc = cc & 7;                                    \
            async_copy16(&BT[(size_t)(n0 + row) * K + (kt) + ((kc ^ (row & 7)) * 8)], \
                         &Bs[cc * 8]);                                         \
        }                                                                      \
    }

    STAGE_TILE(0);
    __syncthreads();                      // tile 0 in LDS

    for (int t = 0; t < T; ++t) {
        // read fragments of tile t (compiler waits lgkm for reg deps)
        bf16x8 a[4][2], b[4][2];
#pragma unroll
        for (int i = 0; i < 4; ++i)
#pragma unroll
            for (int kk = 0; kk < 2; ++kk) {
                a[i][kk] = *(const bf16x8*)&As[
                    (wr + i * 16 + lr) * 64 + (((kk * 4 + lk16) ^ sw) * 8)];
                b[i][kk] = *(const bf16x8*)&Bs[
                    (wc + i * 16 + lr) * 64 + (((kk * 4 + lk16) ^ sw) * 8)];
            }
        __syncthreads();                  // ALL waves' reads of tile t done
        if (t + 1 < T) STAGE_TILE((t + 1) * 64);  // safe overwrite; in flight

        __builtin_amdgcn_s_setprio(1);
#pragma unroll
        for (int i = 0; i < 4; ++i)
#pragma unroll
            for (int j = 0; j < 4; ++j)
#pragma unroll
                for (int kk = 0; kk < 2; ++kk)
                    acc[i][j] = __builtin_amdgcn_mfma_f32_16x16x32_bf16(
                        a[i][kk], b[j][kk], acc[i][j], 0, 0, 0);
        __builtin_amdgcn_s_setprio(0);

        __syncthreads();                  // drain (vmcnt 0): tile t+1 landed
    }
#undef STAGE_TILE

    // Epilogue: D[row=(lane>>4)*4+r][col=lane&15] per fragment (m89 map)
#pragma unroll
    for (int j = 0; j < 4; ++j) {
        int col = n0 + wc + j * 16 + lr;
        float bb = bias[col];
#pragma unroll
        for (int i = 0; i < 4; ++i) {
            int rbase = m0 + wr + i * 16 + lk16 * 4;
            f32x4 v = acc[i][j];
#pragma unroll
            for (int r = 0; r < 4; ++r) {
                float val = v[r] + bb;
                if (ADD_RESID) val += bf2f(resid[(size_t)(rbase + r) * N + col]);
                if (RELU) val = fmaxf(val, 0.f);
                C[(size_t)(rbase + r) * N + col] = f2b(val);
            }
        }
    }
}

// ---------------------------------------------------------------------------
// MFMA flash attention — R15-proven: fixed-reference softmax (R10), l via
// ones-MFMA (R15), pipelined K/V staging (R9), XCD decode (R8), QBLK=64.
// (R16's QBLK=128 was part of the regressed bundle -> reverted.)
// ---------------------------------------------------------------------------
__global__ __launch_bounds__(256) void attention_mfma_kernel(
    const u16* __restrict__ qkv, u16* __restrict__ ctx)
{
    __shared__ __align__(16) u16 Ks[2][64 * 64];
    __shared__ __align__(16) u16 Vt[64][72];
    __shared__ __align__(16) u16 Ps[4][16][72];

    const int tid = threadIdx.x;
    const int raw = blockIdx.x;
    const int xcd = raw & 7;
    const int k8  = raw >> 3;
    const int bh  = xcd * 16 + (k8 >> 3);
    const int b = bh >> 3, h = bh & 7;
    const int q0 = (k8 & 7) * 64;

    const int wid = tid >> 6, lane = tid & 63;
    const int lr = lane & 15;
    const int lk16 = lane >> 4;
    const size_t base = (size_t)b * SEQ * 1536;
    const int qrow = wid * 16 + lr;

    // Q fragments in registers
    bf16x8 qf[2];
#pragma unroll
    for (int ks = 0; ks < 2; ++ks)
        qf[ks] = *(const bf16x8*)&qkv[base + (size_t)(q0 + qrow) * 1536 + h * 64
                                      + ks * 32 + lk16 * 8];

    // all-ones bf16 B-fragment (1.0 = 0x3F80)
    bf16x8 ones;
#pragma unroll
    for (int e = 0; e < 8; ++e) ones[e] = (short)0x3F80;

    const int vr0 = tid & 63;
    const int vc0 = (tid >> 6) * 8;
    const int vc1 = 32 + vc0;

    // ---- Prologue: stage tile 0
#pragma unroll
    for (int j = 0; j < 2; ++j) {
        int c = j * 256 + tid;
        int row = c >> 3;
        int sc8 = ((c & 7) ^ (row & 7)) * 8;
        async_copy16(&qkv[base + (size_t)(row) * 1536 + 512 + h * 64 + sc8], &Ks[0][c * 8]);
    }
    us8 v0 = *(const us8*)&qkv[base + (size_t)(vr0) * 1536 + 1024 + h * 64 + vc0];
    us8 v1 = *(const us8*)&qkv[base + (size_t)(vr0) * 1536 + 1024 + h * 64 + vc1];
    __syncthreads();
#pragma unroll
    for (int e = 0; e < 8; ++e) { Vt[vc0 + e][vr0] = v0[e]; Vt[vc1 + e][vr0] = v1[e]; }
    __syncthreads();

    f32x4 l_acc = {};
    f32x4 o_acc[4] = {};
    const float SC2 = 0.18033688011112042f;   // 0.125 * log2(e)

    for (int t = 0; t < SEQ / 64; ++t) {
        const int cur = t & 1;
        const bool more = (t + 1 < SEQ / 64);
        if (more) {
            const int kt1 = (t + 1) * 64;
#pragma unroll
            for (int j = 0; j < 2; ++j) {
                int c = j * 256 + tid;
                int row = c >> 3;
                int sc8 = ((c & 7) ^ (row & 7)) * 8;
                async_copy16(&qkv[base + (size_t)(kt1 + row) * 1536 + 512 + h * 64 + sc8],
                             &Ks[cur ^ 1][c * 8]);
            }
            v0 = *(const us8*)&qkv[base + (size_t)(kt1 + vr0) * 1536 + 1024 + h * 64 + vc0];
            v1 = *(const us8*)&qkv[base + (size_t)(kt1 + vr0) * 1536 + 1024 + h * 64 + vc1];
        }

        // QK^T on tile t
        f32x4 sc[4] = {};
#pragma unroll
        for (int ks = 0; ks < 2; ++ks) {
#pragma unroll
            for (int j = 0; j < 4; ++j) {
                int krow = j * 16 + lr;
                bf16x8 bk = *(const bf16x8*)&Ks[cur][krow * 64 + ((ks * 4 + lk16) ^ (krow & 7)) * 8];
                sc[j] = __builtin_amdgcn_mfma_f32_16x16x32_bf16(qf[ks], bk, sc[j], 0, 0, 0);
            }
        }

        // fixed-reference softmax: p = 2^(s*SC2), straight to Ps (bf16)
#pragma unroll
        for (int j = 0; j < 4; ++j)
#pragma unroll
            for (int r = 0; r < 4; ++r)
                Ps[wid][lk16 * 4 + r][j * 16 + lr] =
                    f2b(__builtin_amdgcn_exp2f(sc[j][r] * SC2));

        // PV on tile t + l via ones-MFMA (row-sums of P, C-layout matches o)
#pragma unroll
        for (int kk = 0; kk < 2; ++kk) {
            bf16x8 ap = *(const bf16x8*)&Ps[wid][lr][kk * 32 + lk16 * 8];
            l_acc = __builtin_amdgcn_mfma_f32_16x16x32_bf16(ap, ones, l_acc, 0, 0, 0);
#pragma unroll
            for (int j2 = 0; j2 < 4; ++j2) {
                bf16x8 bv = *(const bf16x8*)&Vt[j2 * 16 + lr][kk * 32 + lk16 * 8];
                o_acc[j2] = __builtin_amdgcn_mfma_f32_16x16x32_bf16(ap, bv, o_acc[j2], 0, 0, 0);
            }
        }

        __syncthreads();
        if (more) {
#pragma unroll
            for (int e = 0; e < 8; ++e) { Vt[vc0 + e][vr0] = v0[e]; Vt[vc1 + e][vr0] = v1[e]; }
        }
        __syncthreads();
    }

    // epilogue: out[q][d] = o/l, bf16
#pragma unroll
    for (int r = 0; r < 4; ++r) {
        float inv = 1.f / l_acc[r];
        int t = b * SEQ + q0 + wid * 16 + lk16 * 4 + r;
        u16* op = &ctx[(size_t)t * DMODEL + h * 64];
#pragma unroll
        for (int j2 = 0; j2 < 4; ++j2)
            op[j2 * 16 + lr] = f2b(o_acc[j2][r] * inv);
    }
}

// ---------------------------------------------------------------------------
// LayerNorm over pre-summed bf16 input (residual fused into GEMM epilogue).
// ---------------------------------------------------------------------------
__global__ __launch_bounds__(256) void ln_kernel(
    const u16* __restrict__ sum_in, u16* __restrict__ xb,
    const float* __restrict__ gamma, const float* __restrict__ beta)
{
    const int wave = threadIdx.x >> 6, lane = threadIdx.x & 63;
    const int t = blockIdx.x * 4 + wave;
    const u16* sr = sum_in + (size_t)t * DMODEL;
    u16* xbr = xb + (size_t)t * DMODEL;

    us8 a = *(const us8*)&sr[lane * 8];
    float v[8];
    float sum = 0.f;
#pragma unroll
    for (int i = 0; i < 8; ++i) { v[i] = bf2f(a[i]); sum += v[i]; }
#pragma unroll
    for (int off = 32; off; off >>= 1) sum += __shfl_xor(sum, off);
    float mean = sum * (1.f / DMODEL);
    float vs = 0.f;
#pragma unroll
    for (int i = 0; i < 8; ++i) {
        float d = v[i] - mean;
        vs += d * d;
    }
#pragma unroll
    for (int off = 32; off; off >>= 1) vs += __shfl_xor(vs, off);
    float rstd = rsqrtf(vs * (1.f / DMODEL) + 1e-5f);
    us8 o;
#pragma unroll
    for (int i = 0; i < 8; ++i) {
        int d = lane * 8 + i;
        o[i] = f2b((v[i] - mean) * rstd * gamma[d] + beta[d]);
    }
    *(us8*)&xbr[lane * 8] = o;
}

// ---------------------------------------------------------------------------
// Output projection: reads bf16 xb
// ---------------------------------------------------------------------------
__global__ __launch_bounds__(256) void out_kernel(
    const u16* __restrict__ xb, const float* __restrict__ w,
    const float* __restrict__ b, float* __restrict__ out)
{
    const int wave = threadIdx.x >> 6, lane = threadIdx.x & 63;
    const int t = blockIdx.x * 4 + wave;
    const u16* xr = xb + (size_t)t * DMODEL;
    us8 a = *(const us8*)&xr[lane * 8];
    float acc = 0.f;
#pragma unroll
    for (int i = 0; i < 8; ++i)
        acc += bf2f(a[i]) * w[lane * 8 + i];
#pragma unroll
    for (int off = 32; off; off >>= 1) acc += __shfl_xor(acc, off);
    if (lane == 0) out[t] = acc + b[0];
}

// ---------------------------------------------------------------------------
extern "C" void kernel_launch(void* const* d_in, const int* in_sizes, int n_in,
                              void* d_out, int out_size, void* d_ws, size_t ws_size,
                              hipStream_t stream)
{
    const float* features = (const float*)d_in[0];
    const int*   pos      = (const int*)  d_in[1];
    const float* w_in     = (const float*)d_in[2];
    const float* b_in     = (const float*)d_in[3];
    const float* qkv_w    = (const float*)d_in[4];
    const float* qkv_b    = (const float*)d_in[5];
    const float* ow       = (const float*)d_in[6];
    const float* ob       = (const float*)d_in[7];
    const float* g1       = (const float*)d_in[8];
    const float* b1       = (const float*)d_in[9];
    const float* ff1w     = (const float*)d_in[10];
    const float* ff1b     = (const float*)d_in[11];
    const float* ff2w     = (const float*)d_in[12];
    const float* ff2b     = (const float*)d_in[13];
    const float* g2       = (const float*)d_in[14];
    const float* b2       = (const float*)d_in[15];
    const float* w_out    = (const float*)d_in[16];
    const float* b_out    = (const float*)d_in[17];
    float* out = (float*)d_out;

    char* p = (char*)d_ws;
    auto alloc = [&](size_t bytes) { char* r = p; p += (bytes + 255) & ~(size_t)255; return r; };
    u16*   xb  = (u16*)  alloc((size_t)NTOK * DMODEL * 2);          // 8 MB
    u16*   big = (u16*)  alloc((size_t)NTOK * FFDIM * 2);           // 32 MB
    u16*   ctx = (u16*)  alloc((size_t)NTOK * DMODEL * 2);          // 8 MB
    u16*   tmp = (u16*)  alloc((size_t)NTOK * DMODEL * 2);          // 8 MB
    u16* wqkvT = (u16*)alloc((size_t)NLAYER * DMODEL * 3 * DMODEL * 2);
    u16* owT   = (u16*)alloc((size_t)NLAYER * DMODEL * DMODEL * 2);
    u16* f1wT  = (u16*)alloc((size_t)NLAYER * DMODEL * FFDIM * 2);
    u16* f2wT  = (u16*)alloc((size_t)NLAYER * FFDIM * DMODEL * 2);

    transpose_w_kernel<<<dim3(3 * DMODEL / 32, DMODEL / 32, NLAYER), 256, 0, stream>>>(
        qkv_w, wqkvT, DMODEL, 3 * DMODEL);
    transpose_w_kernel<<<dim3(DMODEL / 32, DMODEL / 32, NLAYER), 256, 0, stream>>>(
        ow, owT, DMODEL, DMODEL);
    transpose_w_kernel<<<dim3(FFDIM / 32, DMODEL / 32, NLAYER), 256, 0, stream>>>(
        ff1w, f1wT, DMODEL, FFDIM);
    transpose_w_kernel<<<dim3(DMODEL / 32, FFDIM / 32, NLAYER), 256, 0, stream>>>(
        ff2w, f2wT, FFDIM, DMODEL);

    embed_kernel<<<(NTOK * DMODEL + 255) / 256, 256, 0, stream>>>(
        features, pos, w_in, b_in, xb);

    for (int l = 0; l < NLAYER; ++l) {
        // qkv = xb @ qkv_w + qkv_b -> bf16 [8192,1536]
        gemm_bk64_kernel<0, 0><<<dim3(3 * DMODEL / 128, NTOK / 128), 256, 0, stream>>>(
            xb, wqkvT + (size_t)l * DMODEL * 3 * DMODEL, qkv_b + (size_t)l * 3 * DMODEL,
            nullptr, big, NTOK, 3 * DMODEL, DMODEL);
        // attention -> ctx bf16  (1D grid: XCD-locality decode in kernel)
        attention_mfma_kernel<<<BATCH * NHEAD * (SEQ / 64), 256, 0, stream>>>(big, ctx);
        // tmp = ctx @ ow + ob + xb   (residual fused, bf16 out)
        gemm_bk64_kernel<0, 1><<<dim3(DMODEL / 128, NTOK / 128), 256, 0, stream>>>(
            ctx, owT + (size_t)l * DMODEL * DMODEL, ob + (size_t)l * DMODEL, xb,
            tmp, NTOK, DMODEL, DMODEL);
        // xb = LN(tmp)
        ln_kernel<<<NTOK / 4, 256, 0, stream>>>(
            tmp, xb, g1 + (size_t)l * DMODEL, b1 + (size_t)l * DMODEL);
        // h = relu(xb @ ff1w + ff1b) -> bf16 [8192,2048]
        gemm_bk64_kernel<1, 0><<<dim3(FFDIM / 128, NTOK / 128), 256, 0, stream>>>(
            xb, f1wT + (size_t)l * DMODEL * FFDIM, ff1b + (size_t)l * FFDIM,
            nullptr, big, NTOK, FFDIM, DMODEL);
        // tmp = h @ ff2w + ff2b + xb  (residual fused, bf16 out)
        gemm_bk64_kernel<0, 1><<<dim3(DMODEL / 128, NTOK / 128), 256, 0, stream>>>(
            big, f2wT + (size_t)l * FFDIM * DMODEL, ff2b + (size_t)l * DMODEL, xb,
            tmp, NTOK, DMODEL, FFDIM);
        // xb = LN(tmp)
        ln_kernel<<<NTOK / 4, 256, 0, stream>>>(
            tmp, xb, g2 + (size_t)l * DMODEL, b2 + (size_t)l * DMODEL);
    }

    out_kernel<<<NTOK / 4, 256, 0, stream>>>(xb, w_out, b_out, out);
}